// Round 10
// baseline (173.135 us; speedup 1.0000x reference)
//
#include <hip/hip_runtime.h>
#include <stdint.h>

namespace {

typedef short bf16x8 __attribute__((ext_vector_type(8)));
typedef float f32x16 __attribute__((ext_vector_type(16)));
typedef unsigned short u16x4 __attribute__((ext_vector_type(4)));

constexpr int BATCH = 16;
constexpr int LQ = 2048;
constexpr int LK = 2048;
constexpr int DIM = 64;
constexpr float SCALE = 0.125f;  // 1/sqrt(64)

// d_ws byte offsets (flag at 0)
constexpr size_t WS_KHI = 1ull << 20;  // 4 MB bf16 K-hi, fragment-ordered
constexpr size_t WS_KLO = 5ull << 20;  // 4 MB bf16 K-lo
constexpr size_t WS_VT = 9ull << 20;   // 4 MB bf16 V, fragment-ordered
constexpr size_t WS_MB = 13ull << 20;  // 8.4 MB packed mask bits u32[b][row][64]

__global__ void detect_mask_dtype(const uint32_t* __restrict__ mask,
                                  int* __restrict__ flag) {
  __shared__ int bad;
  if (threadIdx.x == 0) bad = 0;
  __syncthreads();
  int my = 0;
  for (int i = threadIdx.x; i < 4096; i += 256) {
    uint32_t w = mask[i];
    if (w > 1u && w != 0x3F800000u) my = 1;
  }
  if (my) atomicOr(&bad, 1);
  __syncthreads();
  if (threadIdx.x == 0) *flag = bad;  // 1 -> uint8-packed
}

__device__ inline unsigned short f2bf(float x) {  // RNE fp32->bf16
  union { float f; unsigned u; } c;
  c.f = x;
  unsigned r = c.u + 0x7FFFu + ((c.u >> 16) & 1u);
  return (unsigned short)(r >> 16);
}
__device__ inline float bf2f(unsigned short h) {
  union { float f; unsigned u; } c;
  c.u = (unsigned)h << 16;
  return c.f;
}
__device__ inline int cvt_pk_bf16(float lo, float hi) {
  int d;
  asm("v_cvt_pk_bf16_f32 %0, %1, %2" : "=v"(d) : "v"(lo), "v"(hi));
  return d;
}

// mfma_f32_32x32x16_bf16: A m=l&31 k=(l>>5)*8+e; B n=l&31 same k;
// C/D col n=l&31, row m=(reg&3)+8*(reg>>2)+4*(l>>5)  [verified; R8/R9 PASS]

// Fused prep: blocks [0,2048) = K frags, [2048,2560) = V frags,
// [2560,4608) = mask pack. Mask branch is a pure streamer (nothing to
// drain its VMEM queue) -> runs at ~fill-kernel HBM BW.
__global__ __launch_bounds__(256) void prep_all(
    const float* __restrict__ kp, const float* __restrict__ vp,
    const uint32_t* __restrict__ maskp, const int* __restrict__ flagp,
    unsigned short* __restrict__ khi, unsigned short* __restrict__ klo,
    unsigned short* __restrict__ vt, uint32_t* __restrict__ mpk) {
  const int blk = blockIdx.x;
  if (blk < 2048) {
    // ---- K -> fragment-ordered [b][T][f][s][lane][8] (R8-verified) ----
    int idx = blk * 256 + threadIdx.x;
    int b = idx >> 15;
    int rem = idx & 32767;
    int r = rem >> 4;
    int d0 = (rem & 15) * 4;
    float4 kf = *(const float4*)(kp + ((size_t)b * LK + r) * DIM + d0);
    u16x4 hv, lv;
#pragma unroll
    for (int j = 0; j < 4; ++j) {
      float x = (&kf.x)[j];
      unsigned short hh = f2bf(x);
      hv[j] = hh;
      lv[j] = f2bf(x - bf2f(hh));
    }
    int T = r >> 6;
    int rin = r & 63;
    int f = rin >> 5;
    int m = rin & 31;
    int s = d0 >> 4;
    int hi = (d0 >> 3) & 1;
    int e0 = d0 & 7;
    size_t off =
        ((((size_t)(b * 32 + T) * 2 + f) * 4 + s) * 64 + (hi * 32 + m)) * 8 +
        e0;
    *(u16x4*)(khi + off) = hv;
    *(u16x4*)(klo + off) = lv;
  } else if (blk < 2560) {
    // ---- V -> fragment-ordered [b][T][nb][ks][lane][8] (R8-verified) ----
    int idx = (blk - 2048) * 256 + threadIdx.x;
    int b = idx >> 13;
    int rem = idx & 8191;
    int kq = rem >> 4;
    int dq = rem & 15;
    int k0 = kq * 4;
    int T = k0 >> 6;
    int kin = k0 & 63;
    const float* vg = vp + ((size_t)b * LK + k0) * DIM + dq * 4;
    unsigned short tmp[4][4];
#pragma unroll
    for (int j = 0; j < 4; ++j) {
      float4 vf = *(const float4*)(vg + j * DIM);
#pragma unroll
      for (int i2 = 0; i2 < 4; ++i2) tmp[j][i2] = f2bf((&vf.x)[i2]);
    }
    int ks = kin >> 4;
    int hi = (kin >> 3) & 1;
    int e0 = kin & 7;
#pragma unroll
    for (int j2 = 0; j2 < 4; ++j2) {
      int d = dq * 4 + j2;
      int nb = d >> 5;
      u16x4 od = {tmp[0][j2], tmp[1][j2], tmp[2][j2], tmp[3][j2]};
      size_t off = ((((size_t)(b * 32 + T) * 2 + nb) * 4 + ks) * 64 +
                    (hi * 32 + (d & 31))) * 8 + e0;
      *(u16x4*)(vt + off) = od;
    }
  } else {
    // ---- mask -> packed bits: mpk[o], bit j = word o*32+j nonzero ----
    const int gid = (blk - 2560) * 256 + threadIdx.x;  // 524288 threads
    const int isU8 = *flagp;
    if (!isU8) {
#pragma unroll
      for (int i = 0; i < 4; ++i) {
        const size_t o = (size_t)gid + (size_t)i * 524288;
        const uint32_t* src = maskp + o * 32;
        uint4 x0 = *(const uint4*)(src + 0);
        uint4 x1 = *(const uint4*)(src + 4);
        uint4 x2 = *(const uint4*)(src + 8);
        uint4 x3 = *(const uint4*)(src + 12);
        uint4 x4 = *(const uint4*)(src + 16);
        uint4 x5 = *(const uint4*)(src + 20);
        uint4 x6 = *(const uint4*)(src + 24);
        uint4 x7 = *(const uint4*)(src + 28);
        uint32_t bits = 0;
#define NIB(X, SH)                                                       \
  bits |= ((unsigned)((X).x != 0u) | ((unsigned)((X).y != 0u) << 1) |    \
           ((unsigned)((X).z != 0u) << 2) | ((unsigned)((X).w != 0u) << 3)) \
          << (SH)
        NIB(x0, 0); NIB(x1, 4); NIB(x2, 8); NIB(x3, 12);
        NIB(x4, 16); NIB(x5, 20); NIB(x6, 24); NIB(x7, 28);
#undef NIB
        mpk[o] = bits;
      }
    } else {
      const uint8_t* m8 = (const uint8_t*)maskp;
#pragma unroll
      for (int i = 0; i < 4; ++i) {
        const size_t o = (size_t)gid + (size_t)i * 524288;
        const uint8_t* src = m8 + o * 32;
        uint4 x0 = *(const uint4*)(src + 0);
        uint4 x1 = *(const uint4*)(src + 16);
        uint32_t bits = 0;
#pragma unroll
        for (int q = 0; q < 4; ++q) {
          uint32_t w0 = (&x0.x)[q], w1 = (&x1.x)[q];
          uint32_t nib0 = (unsigned)((w0 & 0xFFu) != 0u) |
                          ((unsigned)(((w0 >> 8) & 0xFFu) != 0u) << 1) |
                          ((unsigned)(((w0 >> 16) & 0xFFu) != 0u) << 2) |
                          ((unsigned)(((w0 >> 24) & 0xFFu) != 0u) << 3);
          uint32_t nib1 = (unsigned)((w1 & 0xFFu) != 0u) |
                          ((unsigned)(((w1 >> 8) & 0xFFu) != 0u) << 1) |
                          ((unsigned)(((w1 >> 16) & 0xFFu) != 0u) << 2) |
                          ((unsigned)(((w1 >> 24) & 0xFFu) != 0u) << 3);
          bits |= (nib0 << (q * 4)) | (nib1 << (16 + q * 4));
        }
        mpk[o] = bits;
      }
    }
  }
}

// Main: 1024 blocks x 256 thr. Block = 32 q-rows; 4 waves = 4 k-quarters.
// Barrier-free loop; K/V fragment-ordered from L2; mask bits preloaded
// into registers (static indices only). Epilogue combines quarters via LDS.
__global__ __launch_bounds__(256, 4) void attn_mfma(
    const float* __restrict__ qp, const unsigned short* __restrict__ khi_f,
    const unsigned short* __restrict__ klo_f,
    const unsigned short* __restrict__ vt_f,
    const uint32_t* __restrict__ mpk, float* __restrict__ out) {
  __shared__ __align__(16) float X[3 * 64 * 33];
  __shared__ float den_s[32];

  const int tid = threadIdx.x;
  const int h = tid >> 6;  // k-quarter
  const int l = tid & 63;
  const int m31 = l & 31;
  const int hi = l >> 5;
  // XCD swizzle: 2 batches/XCD -> K/V frags L2-resident
  const int xcd = blockIdx.x & 7;
  const int idx = blockIdx.x >> 3;
  const int b = xcd * 2 + (idx >> 6);
  const int qbase = (idx & 63) * 32;
  const int qrow = qbase + m31;

  // ---- preload this wave's 16 packed mask words (rows=own q-row) ----
  uint32_t mwa[16];
  {
    const uint32_t* mr = mpk + ((size_t)b * LQ + qrow) * 64 + h * 16;
    uint4 a0 = *(const uint4*)(mr + 0);
    uint4 a1 = *(const uint4*)(mr + 4);
    uint4 a2 = *(const uint4*)(mr + 8);
    uint4 a3 = *(const uint4*)(mr + 12);
#pragma unroll
    for (int j = 0; j < 4; ++j) {
      mwa[j] = (&a0.x)[j];
      mwa[4 + j] = (&a1.x)[j];
      mwa[8 + j] = (&a2.x)[j];
      mwa[12 + j] = (&a3.x)[j];
    }
  }

  // ---- Q fragments (hi/lo split), B-operand ----
  bf16x8 qh[4], ql[4];
  {
    const float* qr = qp + ((size_t)b * LQ + qrow) * DIM;
#pragma unroll
    for (int s = 0; s < 4; ++s) {
#pragma unroll
      for (int j2 = 0; j2 < 2; ++j2) {
        float4 x = *(const float4*)(qr + s * 16 + hi * 8 + j2 * 4);
#pragma unroll
        for (int j = 0; j < 4; ++j) {
          float xv = (&x.x)[j];
          unsigned short hh = f2bf(xv);
          qh[s][j2 * 4 + j] = (short)hh;
          ql[s][j2 * 4 + j] = (short)f2bf(xv - bf2f(hh));
        }
      }
    }
  }

  f32x16 oA = (f32x16)(0.f), oB = (f32x16)(0.f);
  float den = 0.f;

#pragma unroll
  for (int t = 0; t < 8; ++t) {
    const int T = h * 8 + t;
    const uint32_t b0 = mwa[t * 2];      // tile cols 0..31  (f=0)
    const uint32_t b1 = mwa[t * 2 + 1];  // tile cols 32..63 (f=1)

    // ---- swapped QK^T: S^T = K*Q^T, 3-term split, dual chains ----
    f32x16 sA = (f32x16)(0.f), sB = (f32x16)(0.f);
#pragma unroll
    for (int s = 0; s < 4; ++s) {
      const size_t o0 = ((((size_t)(b * 32 + T) * 2 + 0) * 4 + s) * 64 + l) * 8;
      const size_t o1 = ((((size_t)(b * 32 + T) * 2 + 1) * 4 + s) * 64 + l) * 8;
      bf16x8 k0h = *(const bf16x8*)(khi_f + o0);
      bf16x8 k0l = *(const bf16x8*)(klo_f + o0);
      bf16x8 k1h = *(const bf16x8*)(khi_f + o1);
      bf16x8 k1l = *(const bf16x8*)(klo_f + o1);
      sA = __builtin_amdgcn_mfma_f32_32x32x16_bf16(k0h, qh[s], sA, 0, 0, 0);
      sB = __builtin_amdgcn_mfma_f32_32x32x16_bf16(k1h, qh[s], sB, 0, 0, 0);
      sA = __builtin_amdgcn_mfma_f32_32x32x16_bf16(k0l, qh[s], sA, 0, 0, 0);
      sB = __builtin_amdgcn_mfma_f32_32x32x16_bf16(k1l, qh[s], sB, 0, 0, 0);
      sA = __builtin_amdgcn_mfma_f32_32x32x16_bf16(k0h, ql[s], sA, 0, 0, 0);
      sB = __builtin_amdgcn_mfma_f32_32x32x16_bf16(k1h, ql[s], sB, 0, 0, 0);
    }

    // ---- mask + exp in-register ----
    const int hi4 = hi * 4;
#pragma unroll
    for (int reg = 0; reg < 16; ++reg) {
      const int crow = (reg & 3) + 8 * (reg >> 2);
      float eA = ((b0 >> (crow + hi4)) & 1u) ? 1.0f : __expf(sA[reg] * SCALE);
      float eB = ((b1 >> (crow + hi4)) & 1u) ? 1.0f : __expf(sB[reg] * SCALE);
      den += eA + eB;
      sA[reg] = eA;
      sB[reg] = eB;
    }

    // ---- P->A frags (cvt_pk + permlane32_swap) + PV ----
#define PV_STEP(SV, A_, KS_)                                                 \
  do {                                                                       \
    int c0x = cvt_pk_bf16(SV[8 * A_ + 0], SV[8 * A_ + 1]);                   \
    int c1x = cvt_pk_bf16(SV[8 * A_ + 2], SV[8 * A_ + 3]);                   \
    int c0y = cvt_pk_bf16(SV[8 * A_ + 4], SV[8 * A_ + 5]);                   \
    int c1y = cvt_pk_bf16(SV[8 * A_ + 6], SV[8 * A_ + 7]);                   \
    asm("v_permlane32_swap_b32 %0, %1" : "+v"(c0x), "+v"(c0y));              \
    asm("v_permlane32_swap_b32 %0, %1" : "+v"(c1x), "+v"(c1y));              \
    union { int d[4]; bf16x8 v; } pa_;                                       \
    pa_.d[0] = c0x; pa_.d[1] = c1x; pa_.d[2] = c0y; pa_.d[3] = c1y;          \
    const size_t vo0 =                                                       \
        ((((size_t)(b * 32 + T) * 2 + 0) * 4 + KS_) * 64 + l) * 8;           \
    const size_t vo1 =                                                       \
        ((((size_t)(b * 32 + T) * 2 + 1) * 4 + KS_) * 64 + l) * 8;           \
    bf16x8 vb0 = *(const bf16x8*)(vt_f + vo0);                               \
    bf16x8 vb1 = *(const bf16x8*)(vt_f + vo1);                               \
    oA = __builtin_amdgcn_mfma_f32_32x32x16_bf16(pa_.v, vb0, oA, 0, 0, 0);   \
    oB = __builtin_amdgcn_mfma_f32_32x32x16_bf16(pa_.v, vb1, oB, 0, 0, 0);   \
  } while (0)

    PV_STEP(sA, 0, 0);
    PV_STEP(sA, 1, 1);
    PV_STEP(sB, 0, 2);
    PV_STEP(sB, 1, 3);
#undef PV_STEP
  }

  // ---- epilogue: combine 4 k-quarters ----
  __syncthreads();
  if (h > 0) {
    float* xp = X + ((size_t)((h - 1) * 64 + l)) * 33;
#pragma unroll
    for (int reg = 0; reg < 16; ++reg) {
      xp[reg] = oA[reg];
      xp[16 + reg] = oB[reg];
    }
    xp[32] = den;
  }
  __syncthreads();
  if (h == 0) {
#pragma unroll
    for (int p = 0; p < 3; ++p) {
      const float* xp = X + ((size_t)(p * 64 + l)) * 33;
#pragma unroll
      for (int reg = 0; reg < 16; ++reg) {
        oA[reg] += xp[reg];
        oB[reg] += xp[16 + reg];
      }
      den += xp[32];
    }
    den += __shfl_xor(den, 32);  // combine hi halves -> full row sum
    if (l < 32) den_s[m31] = 1.0f / den;
    // den_s written+read by same wave; compiler orders via lgkmcnt
    float* ob = out + ((size_t)b * LQ + qbase) * DIM;
#pragma unroll
    for (int reg = 0; reg < 16; ++reg) {
      const int qr2 = (reg & 3) + 8 * (reg >> 2) + hi * 4;
      const float inv = den_s[qr2];
      ob[qr2 * DIM + m31] = oA[reg] * inv;
      ob[qr2 * DIM + 32 + m31] = oB[reg] * inv;
    }
  }
}

}  // namespace

extern "C" void kernel_launch(void* const* d_in, const int* in_sizes, int n_in,
                              void* d_out, int out_size, void* d_ws,
                              size_t ws_size, hipStream_t stream) {
  const float* q = (const float*)d_in[0];
  const float* k = (const float*)d_in[1];
  const float* v = (const float*)d_in[2];
  const uint32_t* mask = (const uint32_t*)d_in[3];
  float* out = (float*)d_out;
  int* flag = (int*)d_ws;
  unsigned short* khi_f = (unsigned short*)((char*)d_ws + WS_KHI);
  unsigned short* klo_f = (unsigned short*)((char*)d_ws + WS_KLO);
  unsigned short* vt_f = (unsigned short*)((char*)d_ws + WS_VT);
  uint32_t* mpk = (uint32_t*)((char*)d_ws + WS_MB);

  detect_mask_dtype<<<1, 256, 0, stream>>>(mask, flag);
  prep_all<<<4608, 256, 0, stream>>>(k, v, mask, flag, khi_f, klo_f, vt_f,
                                     mpk);
  attn_mfma<<<dim3(1024), 256, 0, stream>>>(q, khi_f, klo_f, vt_f, mpk, out);
}

// Round 11
// 130.143 us; speedup vs baseline: 1.3303x; 1.3303x over previous
//
#include <hip/hip_runtime.h>
#include <stdint.h>

namespace {

typedef short bf16x8 __attribute__((ext_vector_type(8)));
typedef float f32x16 __attribute__((ext_vector_type(16)));
typedef unsigned short u16x4 __attribute__((ext_vector_type(4)));

constexpr int BATCH = 16;
constexpr int LQ = 2048;
constexpr int LK = 2048;
constexpr int DIM = 64;
constexpr float SCALE = 0.125f;  // 1/sqrt(64)

// d_ws byte offsets (flag at 0)
constexpr size_t WS_KHI = 1ull << 20;  // 4 MB bf16 K-hi, fragment-ordered
constexpr size_t WS_KLO = 5ull << 20;  // 4 MB bf16 K-lo
constexpr size_t WS_VT = 9ull << 20;   // 4 MB bf16 V, fragment-ordered
constexpr size_t WS_MB = 13ull << 20;  // 8.4 MB packed mask bits u32[b][row][64]

__global__ void detect_mask_dtype(const uint32_t* __restrict__ mask,
                                  int* __restrict__ flag) {
  __shared__ int bad;
  if (threadIdx.x == 0) bad = 0;
  __syncthreads();
  int my = 0;
  for (int i = threadIdx.x; i < 4096; i += 256) {
    uint32_t w = mask[i];
    if (w > 1u && w != 0x3F800000u) my = 1;
  }
  if (my) atomicOr(&bad, 1);
  __syncthreads();
  if (threadIdx.x == 0) *flag = bad;  // 1 -> uint8-packed
}

__device__ inline unsigned short f2bf(float x) {  // RNE fp32->bf16
  union { float f; unsigned u; } c;
  c.f = x;
  unsigned r = c.u + 0x7FFFu + ((c.u >> 16) & 1u);
  return (unsigned short)(r >> 16);
}
__device__ inline float bf2f(unsigned short h) {
  union { float f; unsigned u; } c;
  c.u = (unsigned)h << 16;
  return c.f;
}
__device__ inline int cvt_pk_bf16(float lo, float hi) {
  int d;
  asm("v_cvt_pk_bf16_f32 %0, %1, %2" : "=v"(d) : "v"(lo), "v"(hi));
  return d;
}

// mfma_f32_32x32x16_bf16: A m=l&31 k=(l>>5)*8+e; B n=l&31 same k;
// C/D col n=l&31, row m=(reg&3)+8*(reg>>2)+4*(l>>5)  [verified; R8-R10 PASS]

// Fused prep (verified R10): blocks [0,2048) K frags, [2048,2560) V frags,
// [2560,4608) mask pack (pure streamer -> ~fill-kernel HBM BW).
__global__ __launch_bounds__(256) void prep_all(
    const float* __restrict__ kp, const float* __restrict__ vp,
    const uint32_t* __restrict__ maskp, const int* __restrict__ flagp,
    unsigned short* __restrict__ khi, unsigned short* __restrict__ klo,
    unsigned short* __restrict__ vt, uint32_t* __restrict__ mpk) {
  const int blk = blockIdx.x;
  if (blk < 2048) {
    int idx = blk * 256 + threadIdx.x;
    int b = idx >> 15;
    int rem = idx & 32767;
    int r = rem >> 4;
    int d0 = (rem & 15) * 4;
    float4 kf = *(const float4*)(kp + ((size_t)b * LK + r) * DIM + d0);
    u16x4 hv, lv;
#pragma unroll
    for (int j = 0; j < 4; ++j) {
      float x = (&kf.x)[j];
      unsigned short hh = f2bf(x);
      hv[j] = hh;
      lv[j] = f2bf(x - bf2f(hh));
    }
    int T = r >> 6;
    int rin = r & 63;
    int f = rin >> 5;
    int m = rin & 31;
    int s = d0 >> 4;
    int hi = (d0 >> 3) & 1;
    int e0 = d0 & 7;
    size_t off =
        ((((size_t)(b * 32 + T) * 2 + f) * 4 + s) * 64 + (hi * 32 + m)) * 8 +
        e0;
    *(u16x4*)(khi + off) = hv;
    *(u16x4*)(klo + off) = lv;
  } else if (blk < 2560) {
    int idx = (blk - 2048) * 256 + threadIdx.x;
    int b = idx >> 13;
    int rem = idx & 8191;
    int kq = rem >> 4;
    int dq = rem & 15;
    int k0 = kq * 4;
    int T = k0 >> 6;
    int kin = k0 & 63;
    const float* vg = vp + ((size_t)b * LK + k0) * DIM + dq * 4;
    unsigned short tmp[4][4];
#pragma unroll
    for (int j = 0; j < 4; ++j) {
      float4 vf = *(const float4*)(vg + j * DIM);
#pragma unroll
      for (int i2 = 0; i2 < 4; ++i2) tmp[j][i2] = f2bf((&vf.x)[i2]);
    }
    int ks = kin >> 4;
    int hi = (kin >> 3) & 1;
    int e0 = kin & 7;
#pragma unroll
    for (int j2 = 0; j2 < 4; ++j2) {
      int d = dq * 4 + j2;
      int nb = d >> 5;
      u16x4 od = {tmp[0][j2], tmp[1][j2], tmp[2][j2], tmp[3][j2]};
      size_t off = ((((size_t)(b * 32 + T) * 2 + nb) * 4 + ks) * 64 +
                    (hi * 32 + (d & 31))) * 8 + e0;
      *(u16x4*)(vt + off) = od;
    }
  } else {
    const int gid = (blk - 2560) * 256 + threadIdx.x;
    const int isU8 = *flagp;
    if (!isU8) {
#pragma unroll
      for (int i = 0; i < 4; ++i) {
        const size_t o = (size_t)gid + (size_t)i * 524288;
        const uint32_t* src = maskp + o * 32;
        uint4 x0 = *(const uint4*)(src + 0);
        uint4 x1 = *(const uint4*)(src + 4);
        uint4 x2 = *(const uint4*)(src + 8);
        uint4 x3 = *(const uint4*)(src + 12);
        uint4 x4 = *(const uint4*)(src + 16);
        uint4 x5 = *(const uint4*)(src + 20);
        uint4 x6 = *(const uint4*)(src + 24);
        uint4 x7 = *(const uint4*)(src + 28);
        uint32_t bits = 0;
#define NIB(X, SH)                                                          \
  bits |= ((unsigned)((X).x != 0u) | ((unsigned)((X).y != 0u) << 1) |       \
           ((unsigned)((X).z != 0u) << 2) | ((unsigned)((X).w != 0u) << 3)) \
          << (SH)
        NIB(x0, 0); NIB(x1, 4); NIB(x2, 8); NIB(x3, 12);
        NIB(x4, 16); NIB(x5, 20); NIB(x6, 24); NIB(x7, 28);
#undef NIB
        mpk[o] = bits;
      }
    } else {
      const uint8_t* m8 = (const uint8_t*)maskp;
#pragma unroll
      for (int i = 0; i < 4; ++i) {
        const size_t o = (size_t)gid + (size_t)i * 524288;
        const uint8_t* src = m8 + o * 32;
        uint4 x0 = *(const uint4*)(src + 0);
        uint4 x1 = *(const uint4*)(src + 16);
        uint32_t bits = 0;
#pragma unroll
        for (int q = 0; q < 4; ++q) {
          uint32_t w0 = (&x0.x)[q], w1 = (&x1.x)[q];
          uint32_t nib0 = (unsigned)((w0 & 0xFFu) != 0u) |
                          ((unsigned)(((w0 >> 8) & 0xFFu) != 0u) << 1) |
                          ((unsigned)(((w0 >> 16) & 0xFFu) != 0u) << 2) |
                          ((unsigned)(((w0 >> 24) & 0xFFu) != 0u) << 3);
          uint32_t nib1 = (unsigned)((w1 & 0xFFu) != 0u) |
                          ((unsigned)(((w1 >> 8) & 0xFFu) != 0u) << 1) |
                          ((unsigned)(((w1 >> 16) & 0xFFu) != 0u) << 2) |
                          ((unsigned)(((w1 >> 24) & 0xFFu) != 0u) << 3);
          bits |= (nib0 << (q * 4)) | (nib1 << (16 + q * 4));
        }
        mpk[o] = bits;
      }
    }
  }
}

// Main: 1024 blocks x 256 thr, 2 blocks/CU (8 waves/CU, 256-VGPR budget).
// Wave = 32 q-rows x k-quarter. Explicit 1-tile-ahead register pipeline:
// V(t) in flight under QK(t); K(t+1) in flight under exp+PV(t).
__global__ __launch_bounds__(256, 2) void attn_mfma(
    const float* __restrict__ qp, const unsigned short* __restrict__ khi_f,
    const unsigned short* __restrict__ klo_f,
    const unsigned short* __restrict__ vt_f,
    const uint32_t* __restrict__ mpk, float* __restrict__ out) {
  __shared__ __align__(16) float X[3 * 64 * 33];
  __shared__ float den_s[32];

  const int tid = threadIdx.x;
  const int h = tid >> 6;  // k-quarter
  const int l = tid & 63;
  const int m31 = l & 31;
  const int hi = l >> 5;
  const int xcd = blockIdx.x & 7;
  const int idx = blockIdx.x >> 3;
  const int b = xcd * 2 + (idx >> 6);
  const int qbase = (idx & 63) * 32;
  const int qrow = qbase + m31;

  // Fragment base pointers (halfword): off(T,c) = T*4096 + c*512 + l*8
  const unsigned short* kbh =
      khi_f + (size_t)(b * 32 + h * 8) * 4096 + (size_t)l * 8;
  const unsigned short* kbl =
      klo_f + (size_t)(b * 32 + h * 8) * 4096 + (size_t)l * 8;
  const unsigned short* vbb =
      vt_f + (size_t)(b * 32 + h * 8) * 4096 + (size_t)l * 8;
  const uint32_t* mrow = mpk + ((size_t)b * LQ + qrow) * 64 + h * 16;

  // ---- Q fragments (hi/lo split), B-operand ----
  bf16x8 qh[4], ql[4];
  {
    const float* qr = qp + ((size_t)b * LQ + qrow) * DIM;
#pragma unroll
    for (int s = 0; s < 4; ++s) {
#pragma unroll
      for (int j2 = 0; j2 < 2; ++j2) {
        float4 x = *(const float4*)(qr + s * 16 + hi * 8 + j2 * 4);
#pragma unroll
        for (int j = 0; j < 4; ++j) {
          float xv = (&x.x)[j];
          unsigned short hh = f2bf(xv);
          qh[s][j2 * 4 + j] = (short)hh;
          ql[s][j2 * 4 + j] = (short)f2bf(xv - bf2f(hh));
        }
      }
    }
  }

  f32x16 oA = (f32x16)(0.f), oB = (f32x16)(0.f);
  float den = 0.f;

  // pipeline registers (all statically indexed)
  bf16x8 k0h[4], k0l[4], k1h[4], k1l[4];  // K frags, current tile
  bf16x8 vb0[4], vb1[4];                  // V frags, current tile

#define LOAD_K(T)                                                      \
  do {                                                                 \
    const size_t tb_ = (size_t)(T) * 4096;                             \
    _Pragma("unroll") for (int s_ = 0; s_ < 4; ++s_) {                 \
      k0h[s_] = *(const bf16x8*)(kbh + tb_ + s_ * 512);                \
      k0l[s_] = *(const bf16x8*)(kbl + tb_ + s_ * 512);                \
      k1h[s_] = *(const bf16x8*)(kbh + tb_ + 2048 + s_ * 512);         \
      k1l[s_] = *(const bf16x8*)(kbl + tb_ + 2048 + s_ * 512);         \
    }                                                                  \
  } while (0)

#define LOAD_V(T)                                                      \
  do {                                                                 \
    const size_t tb_ = (size_t)(T) * 4096;                             \
    _Pragma("unroll") for (int s_ = 0; s_ < 4; ++s_) {                 \
      vb0[s_] = *(const bf16x8*)(vbb + tb_ + s_ * 512);                \
      vb1[s_] = *(const bf16x8*)(vbb + tb_ + 2048 + s_ * 512);         \
    }                                                                  \
  } while (0)

  uint32_t mb0, mb1;
  {
    uint2 mm = *(const uint2*)(mrow);
    mb0 = mm.x;
    mb1 = mm.y;
  }
  LOAD_K(0);  // prologue (latency exposed once)

#pragma unroll
  for (int t = 0; t < 8; ++t) {
    // V(t): in flight under the QK MFMA block below
    LOAD_V(t);
    uint32_t nmb0 = 0, nmb1 = 0;
    if (t < 7) {
      uint2 mm = *(const uint2*)(mrow + (t + 1) * 2);
      nmb0 = mm.x;
      nmb1 = mm.y;
    }

    // ---- QK^T (consumes K(t), loaded one phase earlier) ----
    f32x16 sA = (f32x16)(0.f), sB = (f32x16)(0.f);
#pragma unroll
    for (int s = 0; s < 4; ++s) {
      sA = __builtin_amdgcn_mfma_f32_32x32x16_bf16(k0h[s], qh[s], sA, 0, 0, 0);
      sB = __builtin_amdgcn_mfma_f32_32x32x16_bf16(k1h[s], qh[s], sB, 0, 0, 0);
      sA = __builtin_amdgcn_mfma_f32_32x32x16_bf16(k0l[s], qh[s], sA, 0, 0, 0);
      sB = __builtin_amdgcn_mfma_f32_32x32x16_bf16(k1l[s], qh[s], sB, 0, 0, 0);
      sA = __builtin_amdgcn_mfma_f32_32x32x16_bf16(k0h[s], ql[s], sA, 0, 0, 0);
      sB = __builtin_amdgcn_mfma_f32_32x32x16_bf16(k1h[s], ql[s], sB, 0, 0, 0);
    }

    // K(t+1): in flight under exp + PV below
    if (t < 7) LOAD_K(t + 1);

    // ---- mask + exp in-register ----
    const int hi4 = hi * 4;
#pragma unroll
    for (int reg = 0; reg < 16; ++reg) {
      const int crow = (reg & 3) + 8 * (reg >> 2);
      float eA = ((mb0 >> (crow + hi4)) & 1u) ? 1.0f : __expf(sA[reg] * SCALE);
      float eB = ((mb1 >> (crow + hi4)) & 1u) ? 1.0f : __expf(sB[reg] * SCALE);
      den += eA + eB;
      sA[reg] = eA;
      sB[reg] = eB;
    }

    // ---- P->A frags (cvt_pk + permlane32_swap) + PV ----
#define PV_STEP(SV, A_, KS_)                                                \
  do {                                                                      \
    int c0x = cvt_pk_bf16(SV[8 * A_ + 0], SV[8 * A_ + 1]);                  \
    int c1x = cvt_pk_bf16(SV[8 * A_ + 2], SV[8 * A_ + 3]);                  \
    int c0y = cvt_pk_bf16(SV[8 * A_ + 4], SV[8 * A_ + 5]);                  \
    int c1y = cvt_pk_bf16(SV[8 * A_ + 6], SV[8 * A_ + 7]);                  \
    asm("v_permlane32_swap_b32 %0, %1" : "+v"(c0x), "+v"(c0y));             \
    asm("v_permlane32_swap_b32 %0, %1" : "+v"(c1x), "+v"(c1y));             \
    union { int d[4]; bf16x8 v; } pa_;                                      \
    pa_.d[0] = c0x; pa_.d[1] = c1x; pa_.d[2] = c0y; pa_.d[3] = c1y;         \
    oA = __builtin_amdgcn_mfma_f32_32x32x16_bf16(pa_.v, vb0[KS_], oA, 0, 0, \
                                                 0);                        \
    oB = __builtin_amdgcn_mfma_f32_32x32x16_bf16(pa_.v, vb1[KS_], oB, 0, 0, \
                                                 0);                        \
  } while (0)

    PV_STEP(sA, 0, 0);
    PV_STEP(sA, 1, 1);
    PV_STEP(sB, 0, 2);
    PV_STEP(sB, 1, 3);
#undef PV_STEP
    mb0 = nmb0;
    mb1 = nmb1;
  }
#undef LOAD_K
#undef LOAD_V

  // ---- epilogue: combine 4 k-quarters ----
  __syncthreads();
  if (h > 0) {
    float* xp = X + ((size_t)((h - 1) * 64 + l)) * 33;
#pragma unroll
    for (int reg = 0; reg < 16; ++reg) {
      xp[reg] = oA[reg];
      xp[16 + reg] = oB[reg];
    }
    xp[32] = den;
  }
  __syncthreads();
  if (h == 0) {
#pragma unroll
    for (int p = 0; p < 3; ++p) {
      const float* xp = X + ((size_t)(p * 64 + l)) * 33;
#pragma unroll
      for (int reg = 0; reg < 16; ++reg) {
        oA[reg] += xp[reg];
        oB[reg] += xp[16 + reg];
      }
      den += xp[32];
    }
    den += __shfl_xor(den, 32);
    if (l < 32) den_s[m31] = 1.0f / den;
    float* ob = out + ((size_t)b * LQ + qbase) * DIM;
#pragma unroll
    for (int reg = 0; reg < 16; ++reg) {
      const int qr2 = (reg & 3) + 8 * (reg >> 2) + hi * 4;
      const float inv = den_s[qr2];
      ob[qr2 * DIM + m31] = oA[reg] * inv;
      ob[qr2 * DIM + 32 + m31] = oB[reg] * inv;
    }
  }
}

}  // namespace

extern "C" void kernel_launch(void* const* d_in, const int* in_sizes, int n_in,
                              void* d_out, int out_size, void* d_ws,
                              size_t ws_size, hipStream_t stream) {
  const float* q = (const float*)d_in[0];
  const float* k = (const float*)d_in[1];
  const float* v = (const float*)d_in[2];
  const uint32_t* mask = (const uint32_t*)d_in[3];
  float* out = (float*)d_out;
  int* flag = (int*)d_ws;
  unsigned short* khi_f = (unsigned short*)((char*)d_ws + WS_KHI);
  unsigned short* klo_f = (unsigned short*)((char*)d_ws + WS_KLO);
  unsigned short* vt_f = (unsigned short*)((char*)d_ws + WS_VT);
  uint32_t* mpk = (uint32_t*)((char*)d_ws + WS_MB);

  detect_mask_dtype<<<1, 256, 0, stream>>>(mask, flag);
  prep_all<<<4608, 256, 0, stream>>>(k, v, mask, flag, khi_f, klo_f, vt_f,
                                     mpk);
  attn_mfma<<<dim3(1024), 256, 0, stream>>>(q, khi_f, klo_f, vt_f, mpk, out);
}

// Round 13
// 110.782 us; speedup vs baseline: 1.5628x; 1.1748x over previous
//
#include <hip/hip_runtime.h>
#include <stdint.h>

namespace {

typedef _Float16 f16x8 __attribute__((ext_vector_type(8)));
typedef __fp16 fp16x2 __attribute__((ext_vector_type(2)));
typedef float f32x16 __attribute__((ext_vector_type(16)));
typedef unsigned short u16x4 __attribute__((ext_vector_type(4)));

constexpr int BATCH = 16;
constexpr int LQ = 2048;
constexpr int LK = 2048;
constexpr int DIM = 64;
constexpr float SCALE = 0.125f;  // 1/sqrt(64)

// d_ws byte offsets (flag at 0)
constexpr size_t WS_KF = 1ull << 20;   // 4 MB fp16 K, fragment-ordered
constexpr size_t WS_VT = 6ull << 20;   // 4 MB fp16 V, fragment-ordered
constexpr size_t WS_MB = 11ull << 20;  // 8.4 MB packed mask bits u32[b][row][64]

__global__ void detect_mask_dtype(const uint32_t* __restrict__ mask,
                                  int* __restrict__ flag) {
  __shared__ int bad;
  if (threadIdx.x == 0) bad = 0;
  __syncthreads();
  int my = 0;
  for (int i = threadIdx.x; i < 4096; i += 256) {
    uint32_t w = mask[i];
    if (w > 1u && w != 0x3F800000u) my = 1;
  }
  if (my) atomicOr(&bad, 1);
  __syncthreads();
  if (threadIdx.x == 0) *flag = bad;  // 1 -> uint8-packed
}

__device__ inline unsigned short f2h_bits(float x) {  // RNE fp32->fp16
  _Float16 h = (_Float16)x;
  union { _Float16 h; unsigned short u; } c;
  c.h = h;
  return c.u;
}
__device__ inline int cvt_pk_f16(float lo, float hi) {  // packed RTZ
  union { fp16x2 h2; int i; } u;
  u.h2 = __builtin_amdgcn_cvt_pkrtz(lo, hi);
  return u.i;
}

// mfma_f32_32x32x16_f16: A m=l&31 k=(l>>5)*8+e; B n=l&31 same k;
// C/D col n=l&31, row m=(reg&3)+8*(reg>>2)+4*(l>>5)
// (identical lane->element mapping to the bf16 shape, verified R8-R11 PASS)

// Fused prep: [0,2048) K frags (fp16 single), [2048,2560) V frags,
// [2560,4608) mask pack (pure streamer at ~fill-kernel HBM BW).
__global__ __launch_bounds__(256) void prep_all(
    const float* __restrict__ kp, const float* __restrict__ vp,
    const uint32_t* __restrict__ maskp, const int* __restrict__ flagp,
    unsigned short* __restrict__ kf, unsigned short* __restrict__ vt,
    uint32_t* __restrict__ mpk) {
  const int blk = blockIdx.x;
  if (blk < 2048) {
    int idx = blk * 256 + threadIdx.x;
    int b = idx >> 15;
    int rem = idx & 32767;
    int r = rem >> 4;
    int d0 = (rem & 15) * 4;
    float4 kv = *(const float4*)(kp + ((size_t)b * LK + r) * DIM + d0);
    u16x4 hv;
#pragma unroll
    for (int j = 0; j < 4; ++j) hv[j] = f2h_bits((&kv.x)[j]);
    int T = r >> 6;
    int rin = r & 63;
    int f = rin >> 5;
    int m = rin & 31;
    int s = d0 >> 4;
    int hi = (d0 >> 3) & 1;
    int e0 = d0 & 7;
    size_t off =
        ((((size_t)(b * 32 + T) * 2 + f) * 4 + s) * 64 + (hi * 32 + m)) * 8 +
        e0;
    *(u16x4*)(kf + off) = hv;
  } else if (blk < 2560) {
    int idx = (blk - 2048) * 256 + threadIdx.x;
    int b = idx >> 13;
    int rem = idx & 8191;
    int kq = rem >> 4;
    int dq = rem & 15;
    int k0 = kq * 4;
    int T = k0 >> 6;
    int kin = k0 & 63;
    const float* vg = vp + ((size_t)b * LK + k0) * DIM + dq * 4;
    unsigned short tmp[4][4];
#pragma unroll
    for (int j = 0; j < 4; ++j) {
      float4 vf = *(const float4*)(vg + j * DIM);
#pragma unroll
      for (int i2 = 0; i2 < 4; ++i2) tmp[j][i2] = f2h_bits((&vf.x)[i2]);
    }
    int ks = kin >> 4;
    int hi = (kin >> 3) & 1;
    int e0 = kin & 7;
#pragma unroll
    for (int j2 = 0; j2 < 4; ++j2) {
      int d = dq * 4 + j2;
      int nb = d >> 5;
      u16x4 od = {tmp[0][j2], tmp[1][j2], tmp[2][j2], tmp[3][j2]};
      size_t off = ((((size_t)(b * 32 + T) * 2 + nb) * 4 + ks) * 64 +
                    (hi * 32 + (d & 31))) * 8 + e0;
      *(u16x4*)(vt + off) = od;
    }
  } else {
    const int gid = (blk - 2560) * 256 + threadIdx.x;
    const int isU8 = *flagp;
    if (!isU8) {
#pragma unroll
      for (int i = 0; i < 4; ++i) {
        const size_t o = (size_t)gid + (size_t)i * 524288;
        const uint32_t* src = maskp + o * 32;
        uint4 x0 = *(const uint4*)(src + 0);
        uint4 x1 = *(const uint4*)(src + 4);
        uint4 x2 = *(const uint4*)(src + 8);
        uint4 x3 = *(const uint4*)(src + 12);
        uint4 x4 = *(const uint4*)(src + 16);
        uint4 x5 = *(const uint4*)(src + 20);
        uint4 x6 = *(const uint4*)(src + 24);
        uint4 x7 = *(const uint4*)(src + 28);
        uint32_t bits = 0;
#define NIB(X, SH)                                                          \
  bits |= ((unsigned)((X).x != 0u) | ((unsigned)((X).y != 0u) << 1) |       \
           ((unsigned)((X).z != 0u) << 2) | ((unsigned)((X).w != 0u) << 3)) \
          << (SH)
        NIB(x0, 0); NIB(x1, 4); NIB(x2, 8); NIB(x3, 12);
        NIB(x4, 16); NIB(x5, 20); NIB(x6, 24); NIB(x7, 28);
#undef NIB
        mpk[o] = bits;
      }
    } else {
      const uint8_t* m8 = (const uint8_t*)maskp;
#pragma unroll
      for (int i = 0; i < 4; ++i) {
        const size_t o = (size_t)gid + (size_t)i * 524288;
        const uint8_t* src = m8 + o * 32;
        uint4 x0 = *(const uint4*)(src + 0);
        uint4 x1 = *(const uint4*)(src + 16);
        uint32_t bits = 0;
#pragma unroll
        for (int q = 0; q < 4; ++q) {
          uint32_t w0 = (&x0.x)[q], w1 = (&x1.x)[q];
          uint32_t nib0 = (unsigned)((w0 & 0xFFu) != 0u) |
                          ((unsigned)(((w0 >> 8) & 0xFFu) != 0u) << 1) |
                          ((unsigned)(((w0 >> 16) & 0xFFu) != 0u) << 2) |
                          ((unsigned)(((w0 >> 24) & 0xFFu) != 0u) << 3);
          uint32_t nib1 = (unsigned)((w1 & 0xFFu) != 0u) |
                          ((unsigned)(((w1 >> 8) & 0xFFu) != 0u) << 1) |
                          ((unsigned)(((w1 >> 16) & 0xFFu) != 0u) << 2) |
                          ((unsigned)(((w1 >> 24) & 0xFFu) != 0u) << 3);
          bits |= (nib0 << (q * 4)) | (nib1 << (16 + q * 4));
        }
        mpk[o] = bits;
      }
    }
  }
}

// Main: 1024 blocks x 256 thr, 2 blocks/CU (8 waves/CU, 256-VGPR budget).
// Wave = 32 q-rows x k-quarter. fp16 single-term QK^T (accuracy protected
// by den >= #masked ~ 1024). Rolled pipeline: V(t) under QK(t); K(t+1)
// issued right after QK(t) (single K reg set, WAR-safe), lands under exp+PV.
__global__ __launch_bounds__(256, 2) void attn_mfma(
    const float* __restrict__ qp, const unsigned short* __restrict__ kf_g,
    const unsigned short* __restrict__ vt_g,
    const uint32_t* __restrict__ mpk, float* __restrict__ out) {
  __shared__ __align__(16) float X[3 * 64 * 33];
  __shared__ float den_s[32];

  const int tid = threadIdx.x;
  const int h = tid >> 6;  // k-quarter
  const int l = tid & 63;
  const int m31 = l & 31;
  const int hi = l >> 5;
  const int xcd = blockIdx.x & 7;
  const int idx = blockIdx.x >> 3;
  const int b = xcd * 2 + (idx >> 6);
  const int qbase = (idx & 63) * 32;
  const int qrow = qbase + m31;

  // Fragment bases (halfword): tile stride 4096; f-block stride 2048;
  // s stride 512; lane offset l*8.
  const unsigned short* kb =
      kf_g + (size_t)(b * 32 + h * 8) * 4096 + (size_t)l * 8;
  const unsigned short* vb =
      vt_g + (size_t)(b * 32 + h * 8) * 4096 + (size_t)l * 8;
  const uint32_t* mrow = mpk + ((size_t)b * LQ + qrow) * 64 + h * 16;

  // ---- Q fragments (fp16), B-operand ----
  f16x8 qf[4];
  {
    const float* qr = qp + ((size_t)b * LQ + qrow) * DIM;
#pragma unroll
    for (int s = 0; s < 4; ++s) {
#pragma unroll
      for (int j2 = 0; j2 < 2; ++j2) {
        float4 x = *(const float4*)(qr + s * 16 + hi * 8 + j2 * 4);
#pragma unroll
        for (int j = 0; j < 4; ++j) qf[s][j2 * 4 + j] = (_Float16)(&x.x)[j];
      }
    }
  }

  f32x16 oA = (f32x16)(0.f), oB = (f32x16)(0.f);
  float denA = 0.f, denB = 0.f;

  // pipeline registers (static names only)
  f16x8 kc0[4], kc1[4];  // K frags, current tile (f=0 / f=1)
  f16x8 vb0[4], vb1[4];  // V frags, current tile

  // prologue: K(0), mask(0)
#pragma unroll
  for (int s = 0; s < 4; ++s) {
    kc0[s] = *(const f16x8*)(kb + s * 512);
    kc1[s] = *(const f16x8*)(kb + 2048 + s * 512);
  }
  uint32_t mb0, mb1;
  {
    uint2 mm = *(const uint2*)(mrow);
    mb0 = mm.x;
    mb1 = mm.y;
  }

  for (int t = 0; t < 8; ++t) {  // rolled: no unroll, no hoist-all
    const size_t tb = (size_t)t * 4096;
    // V(t): in flight under QK(t)
#pragma unroll
    for (int s = 0; s < 4; ++s) {
      vb0[s] = *(const f16x8*)(vb + tb + s * 512);
      vb1[s] = *(const f16x8*)(vb + tb + 2048 + s * 512);
    }
    uint32_t nmb0 = 0, nmb1 = 0;
    if (t < 7) {
      uint2 mm = *(const uint2*)(mrow + (t + 1) * 2);
      nmb0 = mm.x;
      nmb1 = mm.y;
    }

    // ---- QK^T (fp16 single term) ----
    f32x16 sA = (f32x16)(0.f), sB = (f32x16)(0.f);
    __builtin_amdgcn_s_setprio(1);
#pragma unroll
    for (int s = 0; s < 4; ++s) {
      sA = __builtin_amdgcn_mfma_f32_32x32x16_f16(kc0[s], qf[s], sA, 0, 0, 0);
      sB = __builtin_amdgcn_mfma_f32_32x32x16_f16(kc1[s], qf[s], sB, 0, 0, 0);
    }
    __builtin_amdgcn_s_setprio(0);

    // K(t+1): kc dead after QK issue; loads land under exp+PV
    if (t < 7) {
#pragma unroll
      for (int s = 0; s < 4; ++s) {
        kc0[s] = *(const f16x8*)(kb + tb + 4096 + s * 512);
        kc1[s] = *(const f16x8*)(kb + tb + 4096 + 2048 + s * 512);
      }
    }

    // ---- mask + exp in-register ----
    const int hi4 = hi * 4;
#pragma unroll
    for (int reg = 0; reg < 16; ++reg) {
      const int crow = (reg & 3) + 8 * (reg >> 2);
      float eA = ((mb0 >> (crow + hi4)) & 1u) ? 1.0f : __expf(sA[reg] * SCALE);
      float eB = ((mb1 >> (crow + hi4)) & 1u) ? 1.0f : __expf(sB[reg] * SCALE);
      denA += eA;
      denB += eB;
      sA[reg] = eA;
      sB[reg] = eB;
    }

    // ---- P->A frags (cvt_pkrtz + permlane32_swap) + PV ----
#define PV_STEP(SV, A_, KS_)                                                \
  do {                                                                      \
    int c0x = cvt_pk_f16(SV[8 * A_ + 0], SV[8 * A_ + 1]);                   \
    int c1x = cvt_pk_f16(SV[8 * A_ + 2], SV[8 * A_ + 3]);                   \
    int c0y = cvt_pk_f16(SV[8 * A_ + 4], SV[8 * A_ + 5]);                   \
    int c1y = cvt_pk_f16(SV[8 * A_ + 6], SV[8 * A_ + 7]);                   \
    asm("v_permlane32_swap_b32 %0, %1" : "+v"(c0x), "+v"(c0y));             \
    asm("v_permlane32_swap_b32 %0, %1" : "+v"(c1x), "+v"(c1y));             \
    union { int d[4]; f16x8 v; } pa_;                                       \
    pa_.d[0] = c0x; pa_.d[1] = c1x; pa_.d[2] = c0y; pa_.d[3] = c1y;         \
    oA = __builtin_amdgcn_mfma_f32_32x32x16_f16(pa_.v, vb0[KS_], oA, 0, 0,  \
                                                0);                         \
    oB = __builtin_amdgcn_mfma_f32_32x32x16_f16(pa_.v, vb1[KS_], oB, 0, 0,  \
                                                0);                         \
  } while (0)

    __builtin_amdgcn_s_setprio(1);
    PV_STEP(sA, 0, 0);
    PV_STEP(sA, 1, 1);
    PV_STEP(sB, 0, 2);
    PV_STEP(sB, 1, 3);
    __builtin_amdgcn_s_setprio(0);
#undef PV_STEP
    mb0 = nmb0;
    mb1 = nmb1;
  }

  // ---- epilogue: combine 4 k-quarters ----
  float den = denA + denB;
  __syncthreads();
  if (h > 0) {
    float* xp = X + ((size_t)((h - 1) * 64 + l)) * 33;
#pragma unroll
    for (int reg = 0; reg < 16; ++reg) {
      xp[reg] = oA[reg];
      xp[16 + reg] = oB[reg];
    }
    xp[32] = den;
  }
  __syncthreads();
  if (h == 0) {
#pragma unroll
    for (int p = 0; p < 3; ++p) {
      const float* xp = X + ((size_t)(p * 64 + l)) * 33;
#pragma unroll
      for (int reg = 0; reg < 16; ++reg) {
        oA[reg] += xp[reg];
        oB[reg] += xp[16 + reg];
      }
      den += xp[32];
    }
    den += __shfl_xor(den, 32);
    if (l < 32) den_s[m31] = 1.0f / den;
    float* ob = out + ((size_t)b * LQ + qbase) * DIM;
#pragma unroll
    for (int reg = 0; reg < 16; ++reg) {
      const int qr2 = (reg & 3) + 8 * (reg >> 2) + hi * 4;
      const float inv = den_s[qr2];
      ob[qr2 * DIM + m31] = oA[reg] * inv;
      ob[qr2 * DIM + 32 + m31] = oB[reg] * inv;
    }
  }
}

}  // namespace

extern "C" void kernel_launch(void* const* d_in, const int* in_sizes, int n_in,
                              void* d_out, int out_size, void* d_ws,
                              size_t ws_size, hipStream_t stream) {
  const float* q = (const float*)d_in[0];
  const float* k = (const float*)d_in[1];
  const float* v = (const float*)d_in[2];
  const uint32_t* mask = (const uint32_t*)d_in[3];
  float* out = (float*)d_out;
  int* flag = (int*)d_ws;
  unsigned short* kf_g = (unsigned short*)((char*)d_ws + WS_KF);
  unsigned short* vt_g = (unsigned short*)((char*)d_ws + WS_VT);
  uint32_t* mpk = (uint32_t*)((char*)d_ws + WS_MB);

  detect_mask_dtype<<<1, 256, 0, stream>>>(mask, flag);
  prep_all<<<4608, 256, 0, stream>>>(k, v, mask, flag, kf_g, vt_g, mpk);
  attn_mfma<<<dim3(1024), 256, 0, stream>>>(q, kf_g, vt_g, mpk, out);
}

// Round 14
// 99.055 us; speedup vs baseline: 1.7479x; 1.1184x over previous
//
#include <hip/hip_runtime.h>
#include <stdint.h>

namespace {

typedef _Float16 f16x8 __attribute__((ext_vector_type(8)));
typedef __fp16 fp16x2 __attribute__((ext_vector_type(2)));
typedef float f32x16 __attribute__((ext_vector_type(16)));
typedef unsigned short u16x4 __attribute__((ext_vector_type(4)));

constexpr int BATCH = 16;
constexpr int LQ = 2048;
constexpr int LK = 2048;
constexpr int DIM = 64;
constexpr float SCALE = 0.125f;  // 1/sqrt(64)

// d_ws byte offsets (flag at 0)
constexpr size_t WS_KF = 1ull << 20;  // 4 MB fp16 K, fragment-ordered
constexpr size_t WS_VT = 6ull << 20;  // 4 MB fp16 V, fragment-ordered

__global__ void detect_mask_dtype(const uint32_t* __restrict__ mask,
                                  int* __restrict__ flag) {
  __shared__ int bad;
  if (threadIdx.x == 0) bad = 0;
  __syncthreads();
  int my = 0;
  for (int i = threadIdx.x; i < 4096; i += 256) {
    uint32_t w = mask[i];
    if (w > 1u && w != 0x3F800000u) my = 1;
  }
  if (my) atomicOr(&bad, 1);
  __syncthreads();
  if (threadIdx.x == 0) *flag = bad;  // 1 -> uint8-packed
}

__device__ inline unsigned short f2h_bits(float x) {  // RNE fp32->fp16
  _Float16 h = (_Float16)x;
  union { _Float16 h; unsigned short u; } c;
  c.h = h;
  return c.u;
}
__device__ inline int cvt_pk_f16(float lo, float hi) {  // packed RTZ
  union { fp16x2 h2; int i; } u;
  u.h2 = __builtin_amdgcn_cvt_pkrtz(lo, hi);
  return u.i;
}

// mfma_f32_32x32x16_f16: A m=l&31 k=(l>>5)*8+e; B n=l&31 same k;
// C/D col n=l&31, row m=(reg&3)+8*(reg>>2)+4*(l>>5)  [verified R8-R13 PASS]

// Prep: [0,2048) K frags fp16, [2048,2560) V frags fp16 (verified R13).
__global__ __launch_bounds__(256) void prep_kv(
    const float* __restrict__ kp, const float* __restrict__ vp,
    unsigned short* __restrict__ kf, unsigned short* __restrict__ vt) {
  const int blk = blockIdx.x;
  if (blk < 2048) {
    int idx = blk * 256 + threadIdx.x;
    int b = idx >> 15;
    int rem = idx & 32767;
    int r = rem >> 4;
    int d0 = (rem & 15) * 4;
    float4 kv = *(const float4*)(kp + ((size_t)b * LK + r) * DIM + d0);
    u16x4 hv;
#pragma unroll
    for (int j = 0; j < 4; ++j) hv[j] = f2h_bits((&kv.x)[j]);
    int T = r >> 6;
    int rin = r & 63;
    int f = rin >> 5;
    int m = rin & 31;
    int s = d0 >> 4;
    int hi = (d0 >> 3) & 1;
    int e0 = d0 & 7;
    size_t off =
        ((((size_t)(b * 32 + T) * 2 + f) * 4 + s) * 64 + (hi * 32 + m)) * 8 +
        e0;
    *(u16x4*)(kf + off) = hv;
  } else {
    int idx = (blk - 2048) * 256 + threadIdx.x;
    int b = idx >> 13;
    int rem = idx & 8191;
    int kq = rem >> 4;
    int dq = rem & 15;
    int k0 = kq * 4;
    int T = k0 >> 6;
    int kin = k0 & 63;
    const float* vg = vp + ((size_t)b * LK + k0) * DIM + dq * 4;
    unsigned short tmp[4][4];
#pragma unroll
    for (int j = 0; j < 4; ++j) {
      float4 vf = *(const float4*)(vg + j * DIM);
#pragma unroll
      for (int i2 = 0; i2 < 4; ++i2) tmp[j][i2] = f2h_bits((&vf.x)[i2]);
    }
    int ks = kin >> 4;
    int hi = (kin >> 3) & 1;
    int e0 = kin & 7;
#pragma unroll
    for (int j2 = 0; j2 < 4; ++j2) {
      int d = dq * 4 + j2;
      int nb = d >> 5;
      u16x4 od = {tmp[0][j2], tmp[1][j2], tmp[2][j2], tmp[3][j2]};
      size_t off = ((((size_t)(b * 32 + T) * 2 + nb) * 4 + ks) * 64 +
                    (hi * 32 + (d & 31))) * 8 + e0;
      *(u16x4*)(vt + off) = od;
    }
  }
}

// Main: 1024 blocks x 256 thr, 2 blocks/CU. Phase 0: block packs its OWN
// 32 mask rows (256 KB raw -> 8 KB LDS bits) -- block-exclusive, so blocks
// pipeline naturally: some stream mask at HBM BW while others compute.
// Compute: R13's fp16 pipelined swapped-QK^T core; mask = 1 u64 LDS read
// per tile (2-way broadcast, free).
__global__ __launch_bounds__(256, 2) void attn_mfma(
    const float* __restrict__ qp, const unsigned short* __restrict__ kf_g,
    const unsigned short* __restrict__ vt_g,
    const uint32_t* __restrict__ maskp, const int* __restrict__ flagp,
    float* __restrict__ out) {
  // arena alias: compute phase = MbT u64[32 T][32 row] (8 KB);
  // epilogue (after barrier) = X float[3*64*33] (25.3 KB).
  __shared__ __align__(16) unsigned char arena[3 * 64 * 33 * 4];
  __shared__ float den_s[32];
  unsigned long long* MbT = (unsigned long long*)arena;
  float* X = (float*)arena;

  const int tid = threadIdx.x;
  const int h = tid >> 6;  // k-quarter
  const int l = tid & 63;
  const int m31 = l & 31;
  const int hi = l >> 5;
  const int xcd = blockIdx.x & 7;
  const int idx = blockIdx.x >> 3;
  const int b = xcd * 2 + (idx >> 6);
  const int qbase = (idx & 63) * 32;
  const int qrow = qbase + m31;
  const int isU8 = *flagp;

  // ---- phase 0: pack own mask rows -> MbT[T][row] (R9-verified) ----
  {
    const int prow = tid >> 3;  // 0..31
    const int pch = tid & 7;    // 256-col chunk
    if (!isU8) {
      const uint32_t* mg =
          maskp + ((size_t)b * LQ + qbase + prow) * LK + pch * 256;
      for (int T4 = 0; T4 < 4; ++T4) {
        uint4 x[16];
#pragma unroll
        for (int i = 0; i < 16; ++i)
          x[i] = *(const uint4*)(mg + T4 * 64 + i * 4);
        unsigned long long bits = 0;
#pragma unroll
        for (int i = 0; i < 16; ++i) {
          unsigned nib = (unsigned)(x[i].x != 0u) |
                         ((unsigned)(x[i].y != 0u) << 1) |
                         ((unsigned)(x[i].z != 0u) << 2) |
                         ((unsigned)(x[i].w != 0u) << 3);
          bits |= (unsigned long long)nib << (4 * i);
        }
        MbT[(pch * 4 + T4) * 32 + prow] = bits;
      }
    } else {
      const uint8_t* mg = (const uint8_t*)maskp +
                          ((size_t)b * LQ + qbase + prow) * LK + pch * 256;
      for (int T4 = 0; T4 < 4; ++T4) {
        uint4 x[4];
#pragma unroll
        for (int i = 0; i < 4; ++i)
          x[i] = *(const uint4*)(mg + T4 * 64 + i * 16);
        unsigned long long bits = 0;
#pragma unroll
        for (int i = 0; i < 4; ++i) {
#pragma unroll
          for (int dd = 0; dd < 4; ++dd) {
            uint32_t wv = (&x[i].x)[dd];
            unsigned nib = (unsigned)((wv & 0xFFu) != 0u) |
                           ((unsigned)(((wv >> 8) & 0xFFu) != 0u) << 1) |
                           ((unsigned)(((wv >> 16) & 0xFFu) != 0u) << 2) |
                           ((unsigned)(((wv >> 24) & 0xFFu) != 0u) << 3);
            bits |= (unsigned long long)nib << (i * 16 + dd * 4);
          }
        }
        MbT[(pch * 4 + T4) * 32 + prow] = bits;
      }
    }
  }
  __syncthreads();

  // Fragment bases (halfword): tile stride 4096; f-block stride 2048.
  const unsigned short* kb =
      kf_g + (size_t)(b * 32 + h * 8) * 4096 + (size_t)l * 8;
  const unsigned short* vb =
      vt_g + (size_t)(b * 32 + h * 8) * 4096 + (size_t)l * 8;

  // ---- Q fragments (fp16), B-operand ----
  f16x8 qf[4];
  {
    const float* qr = qp + ((size_t)b * LQ + qrow) * DIM;
#pragma unroll
    for (int s = 0; s < 4; ++s) {
#pragma unroll
      for (int j2 = 0; j2 < 2; ++j2) {
        float4 x = *(const float4*)(qr + s * 16 + hi * 8 + j2 * 4);
#pragma unroll
        for (int j = 0; j < 4; ++j) qf[s][j2 * 4 + j] = (_Float16)(&x.x)[j];
      }
    }
  }

  f32x16 oA = (f32x16)(0.f), oB = (f32x16)(0.f);
  float denA = 0.f, denB = 0.f;

  f16x8 kc0[4], kc1[4];  // K frags, current tile
  f16x8 vb0[4], vb1[4];  // V frags, current tile

  // prologue: K(0)
#pragma unroll
  for (int s = 0; s < 4; ++s) {
    kc0[s] = *(const f16x8*)(kb + s * 512);
    kc1[s] = *(const f16x8*)(kb + 2048 + s * 512);
  }

  for (int t = 0; t < 8; ++t) {  // rolled
    const size_t tb = (size_t)t * 4096;
    // mask bits for this tile (LDS, 2-way broadcast)
    const unsigned long long mb = MbT[(h * 8 + t) * 32 + m31];
    const uint32_t mb0 = (uint32_t)mb;
    const uint32_t mb1 = (uint32_t)(mb >> 32);
    // V(t): in flight under QK(t)
#pragma unroll
    for (int s = 0; s < 4; ++s) {
      vb0[s] = *(const f16x8*)(vb + tb + s * 512);
      vb1[s] = *(const f16x8*)(vb + tb + 2048 + s * 512);
    }

    // ---- QK^T (fp16 single term) ----
    f32x16 sA = (f32x16)(0.f), sB = (f32x16)(0.f);
    __builtin_amdgcn_s_setprio(1);
#pragma unroll
    for (int s = 0; s < 4; ++s) {
      sA = __builtin_amdgcn_mfma_f32_32x32x16_f16(kc0[s], qf[s], sA, 0, 0, 0);
      sB = __builtin_amdgcn_mfma_f32_32x32x16_f16(kc1[s], qf[s], sB, 0, 0, 0);
    }
    __builtin_amdgcn_s_setprio(0);

    // K(t+1): kc dead after QK issue; loads land under exp+PV
    if (t < 7) {
#pragma unroll
      for (int s = 0; s < 4; ++s) {
        kc0[s] = *(const f16x8*)(kb + tb + 4096 + s * 512);
        kc1[s] = *(const f16x8*)(kb + tb + 4096 + 2048 + s * 512);
      }
    }

    // ---- mask + exp in-register ----
    const int hi4 = hi * 4;
#pragma unroll
    for (int reg = 0; reg < 16; ++reg) {
      const int crow = (reg & 3) + 8 * (reg >> 2);
      float eA = ((mb0 >> (crow + hi4)) & 1u) ? 1.0f : __expf(sA[reg] * SCALE);
      float eB = ((mb1 >> (crow + hi4)) & 1u) ? 1.0f : __expf(sB[reg] * SCALE);
      denA += eA;
      denB += eB;
      sA[reg] = eA;
      sB[reg] = eB;
    }

    // ---- P->A frags (cvt_pkrtz + permlane32_swap) + PV ----
#define PV_STEP(SV, A_, KS_)                                                \
  do {                                                                      \
    int c0x = cvt_pk_f16(SV[8 * A_ + 0], SV[8 * A_ + 1]);                   \
    int c1x = cvt_pk_f16(SV[8 * A_ + 2], SV[8 * A_ + 3]);                   \
    int c0y = cvt_pk_f16(SV[8 * A_ + 4], SV[8 * A_ + 5]);                   \
    int c1y = cvt_pk_f16(SV[8 * A_ + 6], SV[8 * A_ + 7]);                   \
    asm("v_permlane32_swap_b32 %0, %1" : "+v"(c0x), "+v"(c0y));             \
    asm("v_permlane32_swap_b32 %0, %1" : "+v"(c1x), "+v"(c1y));             \
    union { int d[4]; f16x8 v; } pa_;                                       \
    pa_.d[0] = c0x; pa_.d[1] = c1x; pa_.d[2] = c0y; pa_.d[3] = c1y;         \
    oA = __builtin_amdgcn_mfma_f32_32x32x16_f16(pa_.v, vb0[KS_], oA, 0, 0,  \
                                                0);                         \
    oB = __builtin_amdgcn_mfma_f32_32x32x16_f16(pa_.v, vb1[KS_], oB, 0, 0,  \
                                                0);                         \
  } while (0)

    __builtin_amdgcn_s_setprio(1);
    PV_STEP(sA, 0, 0);
    PV_STEP(sA, 1, 1);
    PV_STEP(sB, 0, 2);
    PV_STEP(sB, 1, 3);
    __builtin_amdgcn_s_setprio(0);
#undef PV_STEP
  }

  // ---- epilogue: combine 4 k-quarters (arena becomes X) ----
  float den = denA + denB;
  __syncthreads();
  if (h > 0) {
    float* xp = X + ((size_t)((h - 1) * 64 + l)) * 33;
#pragma unroll
    for (int reg = 0; reg < 16; ++reg) {
      xp[reg] = oA[reg];
      xp[16 + reg] = oB[reg];
    }
    xp[32] = den;
  }
  __syncthreads();
  if (h == 0) {
#pragma unroll
    for (int p = 0; p < 3; ++p) {
      const float* xp = X + ((size_t)(p * 64 + l)) * 33;
#pragma unroll
      for (int reg = 0; reg < 16; ++reg) {
        oA[reg] += xp[reg];
        oB[reg] += xp[16 + reg];
      }
      den += xp[32];
    }
    den += __shfl_xor(den, 32);
    if (l < 32) den_s[m31] = 1.0f / den;
    float* ob = out + ((size_t)b * LQ + qbase) * DIM;
#pragma unroll
    for (int reg = 0; reg < 16; ++reg) {
      const int qr2 = (reg & 3) + 8 * (reg >> 2) + hi * 4;
      const float inv = den_s[qr2];
      ob[qr2 * DIM + m31] = oA[reg] * inv;
      ob[qr2 * DIM + 32 + m31] = oB[reg] * inv;
    }
  }
}

}  // namespace

extern "C" void kernel_launch(void* const* d_in, const int* in_sizes, int n_in,
                              void* d_out, int out_size, void* d_ws,
                              size_t ws_size, hipStream_t stream) {
  const float* q = (const float*)d_in[0];
  const float* k = (const float*)d_in[1];
  const float* v = (const float*)d_in[2];
  const uint32_t* mask = (const uint32_t*)d_in[3];
  float* out = (float*)d_out;
  int* flag = (int*)d_ws;
  unsigned short* kf_g = (unsigned short*)((char*)d_ws + WS_KF);
  unsigned short* vt_g = (unsigned short*)((char*)d_ws + WS_VT);

  detect_mask_dtype<<<1, 256, 0, stream>>>(mask, flag);
  prep_kv<<<2560, 256, 0, stream>>>(k, v, kf_g, vt_g);
  attn_mfma<<<dim3(1024), 256, 0, stream>>>(q, kf_g, vt_g, mask, flag, out);
}

// Round 15
// 83.201 us; speedup vs baseline: 2.0809x; 1.1906x over previous
//
#include <hip/hip_runtime.h>
#include <stdint.h>

namespace {

typedef _Float16 f16x8 __attribute__((ext_vector_type(8)));
typedef __fp16 fp16x2 __attribute__((ext_vector_type(2)));
typedef float f32x16 __attribute__((ext_vector_type(16)));
typedef unsigned short u16x4 __attribute__((ext_vector_type(4)));

constexpr int BATCH = 16;
constexpr int LQ = 2048;
constexpr int LK = 2048;
constexpr int DIM = 64;
constexpr float SCALE = 0.125f;  // 1/sqrt(64)

// d_ws byte offsets (flag at 0)
constexpr size_t WS_KF = 1ull << 20;  // 4 MB fp16 K, fragment-ordered
constexpr size_t WS_VT = 6ull << 20;  // 4 MB fp16 V, fragment-ordered

__device__ inline unsigned short f2h_bits(float x) {  // RNE fp32->fp16
  _Float16 h = (_Float16)x;
  union { _Float16 h; unsigned short u; } c;
  c.h = h;
  return c.u;
}
__device__ inline int cvt_pk_f16(float lo, float hi) {  // packed RTZ
  union { fp16x2 h2; int i; } u;
  u.h2 = __builtin_amdgcn_cvt_pkrtz(lo, hi);
  return u.i;
}

// mfma_f32_32x32x16_f16: A m=l&31 k=(l>>5)*8+e; B n=l&31 same k;
// C/D col n=l&31, row m=(reg&3)+8*(reg>>2)+4*(l>>5)  [verified R8-R14 PASS]

// Prep: [0,2048) K frags fp16, [2048,2560) V frags fp16 (verified R13/R14);
// block 2560 = mask dtype detect (merged to save a launch).
__global__ __launch_bounds__(256) void prep_kv(
    const float* __restrict__ kp, const float* __restrict__ vp,
    const uint32_t* __restrict__ maskp, int* __restrict__ flag,
    unsigned short* __restrict__ kf, unsigned short* __restrict__ vt) {
  const int blk = blockIdx.x;
  if (blk < 2048) {
    int idx = blk * 256 + threadIdx.x;
    int b = idx >> 15;
    int rem = idx & 32767;
    int r = rem >> 4;
    int d0 = (rem & 15) * 4;
    float4 kv = *(const float4*)(kp + ((size_t)b * LK + r) * DIM + d0);
    u16x4 hv;
#pragma unroll
    for (int j = 0; j < 4; ++j) hv[j] = f2h_bits((&kv.x)[j]);
    int T = r >> 6;
    int rin = r & 63;
    int f = rin >> 5;
    int m = rin & 31;
    int s = d0 >> 4;
    int hi = (d0 >> 3) & 1;
    int e0 = d0 & 7;
    size_t off =
        ((((size_t)(b * 32 + T) * 2 + f) * 4 + s) * 64 + (hi * 32 + m)) * 8 +
        e0;
    *(u16x4*)(kf + off) = hv;
  } else if (blk < 2560) {
    int idx = (blk - 2048) * 256 + threadIdx.x;
    int b = idx >> 13;
    int rem = idx & 8191;
    int kq = rem >> 4;
    int dq = rem & 15;
    int k0 = kq * 4;
    int T = k0 >> 6;
    int kin = k0 & 63;
    const float* vg = vp + ((size_t)b * LK + k0) * DIM + dq * 4;
    unsigned short tmp[4][4];
#pragma unroll
    for (int j = 0; j < 4; ++j) {
      float4 vf = *(const float4*)(vg + j * DIM);
#pragma unroll
      for (int i2 = 0; i2 < 4; ++i2) tmp[j][i2] = f2h_bits((&vf.x)[i2]);
    }
    int ks = kin >> 4;
    int hi = (kin >> 3) & 1;
    int e0 = kin & 7;
#pragma unroll
    for (int j2 = 0; j2 < 4; ++j2) {
      int d = dq * 4 + j2;
      int nb = d >> 5;
      u16x4 od = {tmp[0][j2], tmp[1][j2], tmp[2][j2], tmp[3][j2]};
      size_t off = ((((size_t)(b * 32 + T) * 2 + nb) * 4 + ks) * 64 +
                    (hi * 32 + (d & 31))) * 8 + e0;
      *(u16x4*)(vt + off) = od;
    }
  } else {
    // mask dtype detect: u8-packed masks produce words outside {0,1,1.0f}
    __shared__ int bad;
    if (threadIdx.x == 0) bad = 0;
    __syncthreads();
    int my = 0;
    for (int i = threadIdx.x; i < 4096; i += 256) {
      uint32_t w = maskp[i];
      if (w > 1u && w != 0x3F800000u) my = 1;
    }
    if (my) atomicOr(&bad, 1);
    __syncthreads();
    if (threadIdx.x == 0) *flag = bad;
  }
}

// Main: 1024 blocks x 256 thr, 2 blocks/CU (8 waves/CU, 256-VGPR budget).
// Phase 0: the block's 32 mask rows are one CONTIGUOUS 256 KB region --
// stream it linearly (wave instr = 2 KB contiguous; R14's 1KB-stride
// pattern cost ~32x TA requests/instr). Each 32B (8 words) packs to one
// byte of NB[T][row][e2]; compute reads u64 NB[T][row][*] (2-way bcast).
// Compute: R13/R14-verified fp16 pipelined swapped-QK^T core.
__global__ __launch_bounds__(256, 2) void attn_mfma(
    const float* __restrict__ qp, const unsigned short* __restrict__ kf_g,
    const unsigned short* __restrict__ vt_g,
    const uint32_t* __restrict__ maskp, const int* __restrict__ flagp,
    float* __restrict__ out) {
  // arena alias: compute = NB bytes [T:32][row:32][e2:8] (8 KB);
  // epilogue (after barrier) = X float[3*64*33] (25.3 KB).
  __shared__ __align__(16) unsigned char arena[3 * 64 * 33 * 4];
  __shared__ float den_s[32];
  unsigned char* NB = arena;
  float* X = (float*)arena;

  const int tid = threadIdx.x;
  const int h = tid >> 6;  // k-quarter
  const int l = tid & 63;
  const int m31 = l & 31;
  const int hi = l >> 5;
  const int xcd = blockIdx.x & 7;
  const int idx = blockIdx.x >> 3;
  const int b = xcd * 2 + (idx >> 6);
  const int qbase = (idx & 63) * 32;
  const int qrow = qbase + m31;
  const int isU8 = *flagp;

  // ---- phase 0: linear-stream own 32 mask rows -> NB bits ----
  {
    const size_t mbase = ((size_t)b * LQ + qbase) * LK;  // element index
    if (!isU8) {
      const uint32_t* mg = maskp + mbase;
      for (int i = 0; i < 32; ++i) {
        const int u = i * 256 + tid;  // nib-byte index 0..8191
        const uint32_t* src = mg + (size_t)u * 8;
        uint4 x0 = *(const uint4*)(src);
        uint4 x1 = *(const uint4*)(src + 4);
        unsigned bits =
            (unsigned)(x0.x != 0u) | ((unsigned)(x0.y != 0u) << 1) |
            ((unsigned)(x0.z != 0u) << 2) | ((unsigned)(x0.w != 0u) << 3) |
            ((unsigned)(x1.x != 0u) << 4) | ((unsigned)(x1.y != 0u) << 5) |
            ((unsigned)(x1.z != 0u) << 6) | ((unsigned)(x1.w != 0u) << 7);
        const int row = u >> 8;
        const int T = (u >> 3) & 31;
        const int e2 = u & 7;
        NB[(T * 32 + row) * 8 + e2] = (unsigned char)bits;
      }
    } else {
      const uint8_t* mg = (const uint8_t*)maskp + mbase;
      for (int i = 0; i < 8; ++i) {
        const int c = i * 256 + tid;  // 32-byte chunk 0..2047
        const uint8_t* src = mg + (size_t)c * 32;
        uint4 x0 = *(const uint4*)(src);
        uint4 x1 = *(const uint4*)(src + 16);
        uint32_t w32 = 0;
#pragma unroll
        for (int q = 0; q < 4; ++q) {
          uint32_t w0 = (&x0.x)[q], w1 = (&x1.x)[q];
          uint32_t nib0 = (unsigned)((w0 & 0xFFu) != 0u) |
                          ((unsigned)(((w0 >> 8) & 0xFFu) != 0u) << 1) |
                          ((unsigned)(((w0 >> 16) & 0xFFu) != 0u) << 2) |
                          ((unsigned)(((w0 >> 24) & 0xFFu) != 0u) << 3);
          uint32_t nib1 = (unsigned)((w1 & 0xFFu) != 0u) |
                          ((unsigned)(((w1 >> 8) & 0xFFu) != 0u) << 1) |
                          ((unsigned)(((w1 >> 16) & 0xFFu) != 0u) << 2) |
                          ((unsigned)(((w1 >> 24) & 0xFFu) != 0u) << 3);
          w32 |= (nib0 << (q * 4)) | (nib1 << (16 + q * 4));
        }
        const int u0 = c * 4;
        const int row = u0 >> 8;
        const int T = (u0 >> 3) & 31;
        const int e2 = u0 & 7;  // 0 or 4 -> u32-aligned
        *(uint32_t*)&NB[(T * 32 + row) * 8 + e2] = w32;
      }
    }
  }
  __syncthreads();

  // Fragment bases (halfword): tile stride 4096; f-block stride 2048.
  const unsigned short* kb =
      kf_g + (size_t)(b * 32 + h * 8) * 4096 + (size_t)l * 8;
  const unsigned short* vb =
      vt_g + (size_t)(b * 32 + h * 8) * 4096 + (size_t)l * 8;

  // ---- Q fragments (fp16), B-operand ----
  f16x8 qf[4];
  {
    const float* qr = qp + ((size_t)b * LQ + qrow) * DIM;
#pragma unroll
    for (int s = 0; s < 4; ++s) {
#pragma unroll
      for (int j2 = 0; j2 < 2; ++j2) {
        float4 x = *(const float4*)(qr + s * 16 + hi * 8 + j2 * 4);
#pragma unroll
        for (int j = 0; j < 4; ++j) qf[s][j2 * 4 + j] = (_Float16)(&x.x)[j];
      }
    }
  }

  f32x16 oA = (f32x16)(0.f), oB = (f32x16)(0.f);
  float denA = 0.f, denB = 0.f;

  f16x8 kc0[4], kc1[4];  // K frags, current tile
  f16x8 vb0[4], vb1[4];  // V frags, current tile

  // prologue: K(0)
#pragma unroll
  for (int s = 0; s < 4; ++s) {
    kc0[s] = *(const f16x8*)(kb + s * 512);
    kc1[s] = *(const f16x8*)(kb + 2048 + s * 512);
  }

  for (int t = 0; t < 8; ++t) {  // rolled
    const size_t tb = (size_t)t * 4096;
    // mask bits for this tile (LDS u64, 2-way broadcast)
    const unsigned long long mb =
        *(const unsigned long long*)&NB[((h * 8 + t) * 32 + m31) * 8];
    const uint32_t mb0 = (uint32_t)mb;
    const uint32_t mb1 = (uint32_t)(mb >> 32);
    // V(t): in flight under QK(t)
#pragma unroll
    for (int s = 0; s < 4; ++s) {
      vb0[s] = *(const f16x8*)(vb + tb + s * 512);
      vb1[s] = *(const f16x8*)(vb + tb + 2048 + s * 512);
    }

    // ---- QK^T (fp16 single term) ----
    f32x16 sA = (f32x16)(0.f), sB = (f32x16)(0.f);
    __builtin_amdgcn_s_setprio(1);
#pragma unroll
    for (int s = 0; s < 4; ++s) {
      sA = __builtin_amdgcn_mfma_f32_32x32x16_f16(kc0[s], qf[s], sA, 0, 0, 0);
      sB = __builtin_amdgcn_mfma_f32_32x32x16_f16(kc1[s], qf[s], sB, 0, 0, 0);
    }
    __builtin_amdgcn_s_setprio(0);

    // K(t+1): kc dead after QK issue; loads land under exp+PV
    if (t < 7) {
#pragma unroll
      for (int s = 0; s < 4; ++s) {
        kc0[s] = *(const f16x8*)(kb + tb + 4096 + s * 512);
        kc1[s] = *(const f16x8*)(kb + tb + 4096 + 2048 + s * 512);
      }
    }

    // ---- mask + exp in-register ----
    const int hi4 = hi * 4;
#pragma unroll
    for (int reg = 0; reg < 16; ++reg) {
      const int crow = (reg & 3) + 8 * (reg >> 2);
      float eA = ((mb0 >> (crow + hi4)) & 1u) ? 1.0f : __expf(sA[reg] * SCALE);
      float eB = ((mb1 >> (crow + hi4)) & 1u) ? 1.0f : __expf(sB[reg] * SCALE);
      denA += eA;
      denB += eB;
      sA[reg] = eA;
      sB[reg] = eB;
    }

    // ---- P->A frags (cvt_pkrtz + permlane32_swap) + PV ----
#define PV_STEP(SV, A_, KS_)                                                \
  do {                                                                      \
    int c0x = cvt_pk_f16(SV[8 * A_ + 0], SV[8 * A_ + 1]);                   \
    int c1x = cvt_pk_f16(SV[8 * A_ + 2], SV[8 * A_ + 3]);                   \
    int c0y = cvt_pk_f16(SV[8 * A_ + 4], SV[8 * A_ + 5]);                   \
    int c1y = cvt_pk_f16(SV[8 * A_ + 6], SV[8 * A_ + 7]);                   \
    asm("v_permlane32_swap_b32 %0, %1" : "+v"(c0x), "+v"(c0y));             \
    asm("v_permlane32_swap_b32 %0, %1" : "+v"(c1x), "+v"(c1y));             \
    union { int d[4]; f16x8 v; } pa_;                                       \
    pa_.d[0] = c0x; pa_.d[1] = c1x; pa_.d[2] = c0y; pa_.d[3] = c1y;         \
    oA = __builtin_amdgcn_mfma_f32_32x32x16_f16(pa_.v, vb0[KS_], oA, 0, 0,  \
                                                0);                         \
    oB = __builtin_amdgcn_mfma_f32_32x32x16_f16(pa_.v, vb1[KS_], oB, 0, 0,  \
                                                0);                         \
  } while (0)

    __builtin_amdgcn_s_setprio(1);
    PV_STEP(sA, 0, 0);
    PV_STEP(sA, 1, 1);
    PV_STEP(sB, 0, 2);
    PV_STEP(sB, 1, 3);
    __builtin_amdgcn_s_setprio(0);
#undef PV_STEP
  }

  // ---- epilogue: combine 4 k-quarters (arena becomes X) ----
  float den = denA + denB;
  __syncthreads();
  if (h > 0) {
    float* xp = X + ((size_t)((h - 1) * 64 + l)) * 33;
#pragma unroll
    for (int reg = 0; reg < 16; ++reg) {
      xp[reg] = oA[reg];
      xp[16 + reg] = oB[reg];
    }
    xp[32] = den;
  }
  __syncthreads();
  if (h == 0) {
#pragma unroll
    for (int p = 0; p < 3; ++p) {
      const float* xp = X + ((size_t)(p * 64 + l)) * 33;
#pragma unroll
      for (int reg = 0; reg < 16; ++reg) {
        oA[reg] += xp[reg];
        oB[reg] += xp[16 + reg];
      }
      den += xp[32];
    }
    den += __shfl_xor(den, 32);
    if (l < 32) den_s[m31] = 1.0f / den;
    float* ob = out + ((size_t)b * LQ + qbase) * DIM;
#pragma unroll
    for (int reg = 0; reg < 16; ++reg) {
      const int qr2 = (reg & 3) + 8 * (reg >> 2) + hi * 4;
      const float inv = den_s[qr2];
      ob[qr2 * DIM + m31] = oA[reg] * inv;
      ob[qr2 * DIM + 32 + m31] = oB[reg] * inv;
    }
  }
}

}  // namespace

extern "C" void kernel_launch(void* const* d_in, const int* in_sizes, int n_in,
                              void* d_out, int out_size, void* d_ws,
                              size_t ws_size, hipStream_t stream) {
  const float* q = (const float*)d_in[0];
  const float* k = (const float*)d_in[1];
  const float* v = (const float*)d_in[2];
  const uint32_t* mask = (const uint32_t*)d_in[3];
  float* out = (float*)d_out;
  int* flag = (int*)d_ws;
  unsigned short* kf_g = (unsigned short*)((char*)d_ws + WS_KF);
  unsigned short* vt_g = (unsigned short*)((char*)d_ws + WS_VT);

  prep_kv<<<2561, 256, 0, stream>>>(k, v, mask, flag, kf_g, vt_g);
  attn_mfma<<<dim3(1024), 256, 0, stream>>>(q, kf_g, vt_g, mask, flag, out);
}